// Round 9
// baseline (131.850 us; speedup 1.0000x reference)
//
#include <hip/hip_runtime.h>

typedef __bf16 bf16;
typedef bf16 bf16x8 __attribute__((ext_vector_type(8)));
typedef bf16 bf16x4 __attribute__((ext_vector_type(4)));
typedef bf16 bf16x2 __attribute__((ext_vector_type(2)));
typedef float f32x4 __attribute__((ext_vector_type(4)));
typedef unsigned long long u64;
typedef unsigned short u16;

#define B_SZ 8
#define N_SEQ 1024
#define DMODEL 512
#define N_HEADS 8
#define D_HEAD 64
#define M_ROWS 8192   // B_SZ * N_SEQ

// Q pre-scale: 1/sqrt(64) * log2(e), so softmax uses exp2 directly
#define QSCALE 0.18033688011112042f

// ---- workspace layout (bytes) ----
static constexpr size_t OFF_XB   = 0;                                   // bf16 [8192][512]; reused as attn_out later
static constexpr size_t OFF_WQKV = (size_t)M_ROWS * DMODEL * 2;         // bf16 [1536][512]
static constexpr size_t OFF_WO   = OFF_WQKV + (size_t)1536 * 512 * 2;   // bf16 [512][512]
static constexpr size_t OFF_BQKV = OFF_WO + (size_t)512 * 512 * 2;      // f32  [1536]
static constexpr size_t OFF_Q    = OFF_BQKV + 1536 * 4;                 // bf16 [64][1024][64]; later reused as h bf16
static constexpr size_t OFF_K    = OFF_Q + (size_t)64 * 1024 * 64 * 2;
static constexpr size_t OFF_V    = OFF_K + (size_t)64 * 1024 * 64 * 2;  // V^T: bf16 [64 bh][64 d][1024 n]
static constexpr size_t OFF_MASK = OFF_V + (size_t)64 * 1024 * 64 * 2;  // u64 [8][1024][16]

// k_prep block partition (256 threads each)
#define PREP_X_BLK 4096    // 8192*512 elems / 4-per-thread / 256
#define PREP_W_BLK 4102    // (1536*512 + 512*512 + 1536) / 256
#define PREP_M_BLK 32768   // 8*1024*1024 / 256

__device__ __forceinline__ f32x4 mfma16(bf16x8 a, bf16x8 b, f32x4 c) {
  return __builtin_amdgcn_mfma_f32_16x16x32_bf16(a, b, c, 0, 0, 0);
}

// XOR swizzle for [R][64] bf16 LDS tiles (row = 128B): kills the 32-way
// ds_read_b128 column conflict (guide G4 / T2). col, row in elements.
__device__ __forceinline__ int sidx(int row, int col) {
  return (row << 6) + (col ^ ((row & 7) << 3));
}

// async global->LDS, 16B per lane; LDS dest = wave-uniform base + lane*16.
__device__ __forceinline__ void gload16(const void* g, void* l) {
  __builtin_amdgcn_global_load_lds(
      (const __attribute__((address_space(1))) void*)g,
      (__attribute__((address_space(3))) void*)l, 16, 0, 0);
}

// ---- merged prep: cvt x, pack weights/biases, build mask bits ----
__global__ void k_prep(const float* __restrict__ x, const float* __restrict__ adj,
                       const float* __restrict__ Wq, const float* __restrict__ Wk,
                       const float* __restrict__ Wv, const float* __restrict__ Wo,
                       const float* __restrict__ bq, const float* __restrict__ bk,
                       const float* __restrict__ bv,
                       bf16* __restrict__ xb, bf16* __restrict__ wqkv,
                       bf16* __restrict__ wo, float* __restrict__ bqkv,
                       u64* __restrict__ maskb) {
  int b = blockIdx.x;
  if (b < PREP_X_BLK) {                 // x fp32 -> bf16, 4/thread
    int i = b * 256 + threadIdx.x;
    float4 v = reinterpret_cast<const float4*>(x)[i];
    bf16x4 o = { (bf16)v.x, (bf16)v.y, (bf16)v.z, (bf16)v.w };
    *reinterpret_cast<bf16x4*>(xb + (size_t)i * 4) = o;
  } else if (b < PREP_X_BLK + PREP_W_BLK) {  // weights/biases
    int tid = (b - PREP_X_BLK) * 256 + threadIdx.x;
    if (tid < 1536 * 512) {
      int row = tid >> 9;
      const float* Wsrc = row < 512 ? Wq : row < 1024 ? Wk : Wv;
      wqkv[tid] = (bf16)Wsrc[((row & 511) << 9) | (tid & 511)];
    } else if (tid < 1536 * 512 + 512 * 512) {
      int t = tid - 1536 * 512;
      wo[t] = (bf16)Wo[t];
    } else if (tid < 1536 * 512 + 512 * 512 + 1536) {
      int t = tid - (1536 * 512 + 512 * 512);
      bqkv[t] = t < 512 ? bq[t] : t < 1024 ? bk[t - 512] : bv[t - 1024];
    }
  } else {                              // adjacency -> bitmask with self loops
    int idx = (b - (PREP_X_BLK + PREP_W_BLK)) * 256 + threadIdx.x;
    int q = (idx >> 10) & 1023, k = idx & 1023;
    bool pred = (adj[idx] > 0.f) || (q == k);
    u64 bal = __ballot(pred);
    if ((threadIdx.x & 63) == 0) maskb[idx >> 6] = bal;
  }
}

// ---- bf16 MFMA GEMM, m97 structure (unchanged from round 8) ----
__global__ __launch_bounds__(256) void k_gemm(const bf16* __restrict__ A,
    const bf16* __restrict__ W, int ncols, int mode,
    const float* __restrict__ bias, const float* __restrict__ xres,
    bf16* __restrict__ oq, bf16* __restrict__ okk, bf16* __restrict__ ov,
    bf16* __restrict__ oh) {
  __shared__ bf16 Al[128 * 64];
  __shared__ bf16 Bl[128 * 64];
  int nbx = ncols >> 7;
  int bx = blockIdx.x % nbx, by = blockIdx.x / nbx;
  int m0 = by << 7, n0 = bx << 7;
  int tid = threadIdx.x, lane = tid & 63, w = tid >> 6;
  int wr = (w >> 1) << 6, wc = (w & 1) << 6;
  int lrow = lane & 15, lg = lane >> 4, lko = lg * 8;
  int rl = lane >> 3;                   // row-in-group 0..7
  int csw = ((lane & 7) ^ rl) << 3;     // pre-swizzled col (elements)

  const bf16* Asrc = A + (size_t)(m0 + w * 32 + rl) * DMODEL + csw;
  const bf16* Wsrc = W + (size_t)(n0 + w * 32 + rl) * DMODEL + csw;
  bf16* Adst = &Al[(w * 4) * 512];
  bf16* Bdst = &Bl[(w * 4) * 512];

  f32x4 acc[4][4];
#pragma unroll
  for (int i = 0; i < 4; i++)
#pragma unroll
    for (int j = 0; j < 4; j++) acc[i][j] = f32x4{0.f, 0.f, 0.f, 0.f};

  for (int k0 = 0; k0 < DMODEL; k0 += 64) {
    __syncthreads();
#pragma unroll
    for (int i = 0; i < 4; i++) {
      gload16(Asrc + k0 + (size_t)i * 8 * DMODEL, Adst + i * 512);
      gload16(Wsrc + k0 + (size_t)i * 8 * DMODEL, Bdst + i * 512);
    }
    __syncthreads();

    bf16x8 afr[4][2], bfr[4][2];
#pragma unroll
    for (int i = 0; i < 4; i++) {
      afr[i][0] = *reinterpret_cast<const bf16x8*>(&Al[sidx(wr + i * 16 + lrow, lko)]);
      afr[i][1] = *reinterpret_cast<const bf16x8*>(&Al[sidx(wr + i * 16 + lrow, 32 + lko)]);
      bfr[i][0] = *reinterpret_cast<const bf16x8*>(&Bl[sidx(wc + i * 16 + lrow, lko)]);
      bfr[i][1] = *reinterpret_cast<const bf16x8*>(&Bl[sidx(wc + i * 16 + lrow, 32 + lko)]);
    }
#pragma unroll
    for (int i = 0; i < 4; i++)
#pragma unroll
      for (int j = 0; j < 4; j++) {
        acc[i][j] = mfma16(afr[i][0], bfr[j][0], acc[i][j]);
        acc[i][j] = mfma16(afr[i][1], bfr[j][1], acc[i][j]);
      }
  }

  int rbase = lg * 4;
  if (mode == 0) {
#pragma unroll
    for (int i = 0; i < 4; i++) {
      int row0 = m0 + wr + i * 16 + rbase;
#pragma unroll
      for (int j = 0; j < 4; j++) {
        int col = n0 + wc + j * 16 + lrow;
        int which = col >> 9, c2 = col & 511, hh = c2 >> 6, dd = c2 & 63;
        float bi = bias[col];
        if (which == 2) {
          int bb = row0 >> 10, nn = row0 & 1023;
          bf16x4 pack;
#pragma unroll
          for (int r = 0; r < 4; r++) pack[r] = (bf16)(acc[i][j][r] + bi);
          *reinterpret_cast<bf16x4*>(
              &ov[(((size_t)bb * N_HEADS + hh) * D_HEAD + dd) * N_SEQ + nn]) = pack;
        } else {
          bf16* dst = which == 0 ? oq : okk;
          float scl = which == 0 ? QSCALE : 1.0f;
#pragma unroll
          for (int r = 0; r < 4; r++) {
            int gm = row0 + r;
            int bb = gm >> 10, nn = gm & 1023;
            dst[(((size_t)bb * N_HEADS + hh) * N_SEQ + nn) * D_HEAD + dd] =
                (bf16)((acc[i][j][r] + bi) * scl);
          }
        }
      }
    }
  } else {
#pragma unroll
    for (int i = 0; i < 4; i++) {
      int row0 = m0 + wr + i * 16 + rbase;
#pragma unroll
      for (int j = 0; j < 4; j++) {
        int col = n0 + wc + j * 16 + lrow;
        float bi = bias[col];
#pragma unroll
        for (int r = 0; r < 4; r++) {
          int gm = row0 + r;
          float y = acc[i][j][r] + bi + xres[(size_t)gm * DMODEL + col];
          oh[(size_t)gm * DMODEL + col] = (bf16)y;
        }
      }
    }
  }
}

// ---- masked attention: k-split waves, PRIVATE per-wave staging, no barrier ----
// Block = 32 q-rows of one (b,h); wave w owns k-quarter w*16..+15 of every
// 64-k tile, staging its own K[16][64] (swizzled) + V^T[64][16] (linear) into
// a private LDS slice, double-buffered -- NO __syncthreads in the main loop;
// s_waitcnt vmcnt(4) keeps next-tile prefetch in flight (T4). Swapped QK^T
// (mfma(K,Q)) gives S^T at q=lane&15, k_local=lg*4+r; P feeds PV directly as
// B-operand (k_hat=lg*8+j <-> k_local=lg*4+j, j<4; upper half zero), A = V^T
// b64 frags. One barrier at the end: bf16 O^T partials + ls cross-wave reduce
// through the dead staging LDS (chunk-XOR swizzled).
// grid 2048 XCD-swizzled: each XCD owns 8 (b,h) pairs (K/V 2MB < 4MB L2).
__global__ __launch_bounds__(256, 4) void k_attn(const bf16* __restrict__ Qb,
    const bf16* __restrict__ Kb, const bf16* __restrict__ Vtg,
    const u64* __restrict__ maskb, bf16* __restrict__ attn_out) {
  __shared__ bf16 stage[4][2][2048];  // per wave, per buf: [0,1024)=K[16][64], [1024,2048)=V^T[64][16]
  __shared__ float lsp[4][32];

  int bid = blockIdx.x;
  int work = ((bid & 7) << 8) | (bid >> 3);  // XCD swizzle (2048 = 8*256, bijective)
  int bh = work >> 5, qb = work & 31;
  int bb = bh >> 3, hh = bh & 7;
  int tid = threadIdx.x, lane = tid & 63, w = tid >> 6;
  int lrow = lane & 15, lg = lane >> 4;
  int rl = lane >> 3;
  int csw = ((lane & 7) ^ rl) << 3;
  int q0 = qb * 32;

  const bf16* Qh = Qb + (size_t)bh * N_SEQ * D_HEAD;
  const bf16* Kh = Kb + (size_t)bh * N_SEQ * D_HEAD;
  const bf16* Vh = Vtg + (size_t)bh * D_HEAD * N_SEQ;      // [d][n]
  const u16* m16 = (const u16*)(maskb + (size_t)bb * N_SEQ * 16);  // [1024][64 u16]

  // staging sources: K rows (w*16 + i*8 + rl), V^T rows (i*32 + lane/2)
  const bf16* Ks0 = Kh + (size_t)(w * 16 + rl) * D_HEAD + csw;
  const bf16* Vs0 = Vh + (size_t)(lane >> 1) * N_SEQ + w * 16 + (lane & 1) * 8;

  // Q fragments (B-operand of swapped QK^T)
  bf16x8 qf[2][2];
#pragma unroll
  for (int s = 0; s < 2; s++) {
    qf[s][0] = *reinterpret_cast<const bf16x8*>(&Qh[(q0 + s * 16 + lrow) * 64 + lg * 8]);
    qf[s][1] = *reinterpret_cast<const bf16x8*>(&Qh[(q0 + s * 16 + lrow) * 64 + 32 + lg * 8]);
  }

  f32x4 o[4][2];   // [dsub][qsub]: lane holds O^T[d=dsub*16+lg*4+r][q=qsub*16+lrow]
#pragma unroll
  for (int d = 0; d < 4; d++)
#pragma unroll
    for (int s = 0; s < 2; s++) o[d][s] = f32x4{0.f, 0.f, 0.f, 0.f};
  float ls[2] = {0.f, 0.f};

  bf16* mybuf[2] = { &stage[w][0][0], &stage[w][1][0] };

#define STG(buf, kt0_)                                                     \
  {                                                                        \
    gload16(Ks0 + (size_t)(kt0_) * 64, mybuf[buf]);                        \
    gload16(Ks0 + (size_t)(kt0_) * 64 + 512, mybuf[buf] + 512);            \
    gload16(Vs0 + (kt0_), mybuf[buf] + 1024);                              \
    gload16(Vs0 + (kt0_) + 32 * N_SEQ, mybuf[buf] + 1536);                 \
  }

  STG(0, 0);

  for (int kt = 0; kt < 16; kt++) {
    int cur = kt & 1;
    int kt0 = kt << 6;
    // mask u16 (this wave's 16 k-bits) for both q-subtiles
    u16 mw0 = m16[(size_t)(q0 + lrow) * 64 + kt * 4 + w];
    u16 mw1 = m16[(size_t)(q0 + 16 + lrow) * 64 + kt * 4 + w];

    if (kt < 15) STG(cur ^ 1, kt0 + 64);  // prefetch next tile (stays in flight)

    // wait: everything except the 4 newest (next-tile) loads
    if (kt < 15) { asm volatile("s_waitcnt vmcnt(4)" ::: "memory"); }
    else         { asm volatile("s_waitcnt vmcnt(0)" ::: "memory"); }

    const bf16* Kc = mybuf[cur];
    const bf16* Vc = mybuf[cur] + 1024;

    // swapped QK^T: sc[s][r] = S[q=s*16+lrow][k = kt*64 + w*16 + lg*4 + r]
    bf16x8 kf0 = *reinterpret_cast<const bf16x8*>(&Kc[sidx(lrow, lg * 8)]);
    bf16x8 kf1 = *reinterpret_cast<const bf16x8*>(&Kc[sidx(lrow, 32 + lg * 8)]);
    f32x4 sc[2];
#pragma unroll
    for (int s = 0; s < 2; s++) {
      sc[s] = f32x4{0.f, 0.f, 0.f, 0.f};
      sc[s] = mfma16(kf0, qf[s][0], sc[s]);
      sc[s] = mfma16(kf1, qf[s][1], sc[s]);
    }

    // p = mask ? exp2(s) : 0 -> PV B-fragments (j<4 real, upper half zero)
    bf16x8 pa[2] = {{}, {}};
#pragma unroll
    for (int s = 0; s < 2; s++) {
      u16 mw = s == 0 ? mw0 : mw1;
#pragma unroll
      for (int j = 0; j < 4; j++) {
        bool bit = (mw >> (lg * 4 + j)) & 1;
        float pv = bit ? exp2f(sc[s][j]) : 0.f;
        ls[s] += pv;
        pa[s][j] = (bf16)pv;
      }
    }

    // PV: A-frag = V^T_local[dsub*16+lrow][lg*4..+3] (b64), upper half zero
#pragma unroll
    for (int d = 0; d < 4; d++) {
      bf16x4 va = *reinterpret_cast<const bf16x4*>(&Vc[(d * 16 + lrow) * 16 + lg * 4]);
      bf16x8 vf = {va[0], va[1], va[2], va[3],
                   (bf16)0.f, (bf16)0.f, (bf16)0.f, (bf16)0.f};
#pragma unroll
      for (int s = 0; s < 2; s++) o[d][s] = mfma16(vf, pa[s], o[d][s]);
    }
  }
#undef STG

  // ls: reduce over lane-groups (k within quarter) -> lsp[w][q]
  ls[0] += __shfl_xor(ls[0], 16); ls[0] += __shfl_xor(ls[0], 32);
  ls[1] += __shfl_xor(ls[1], 16); ls[1] += __shfl_xor(ls[1], 32);
  if (lane < 16) {
    lsp[w][lrow] = ls[0];
    lsp[w][16 + lrow] = ls[1];
  }

  // O^T partials -> own stage region as bf16 Op[w][q 32][d 64], chunk-swizzled:
  // chunk c = d/4 stored at c^(q&15). Write: c = dsub*4+lg -> conflict-free.
  bf16* Opw = mybuf[0];
#pragma unroll
  for (int d = 0; d < 4; d++)
#pragma unroll
    for (int s = 0; s < 2; s++) {
      bf16x4 pk;
#pragma unroll
      for (int r = 0; r < 4; r++) pk[r] = (bf16)o[d][s][r];
      int q = s * 16 + lrow;
      int cs = (d * 4 + lg) ^ lrow;
      *reinterpret_cast<bf16x4*>(&Opw[q * 64 + cs * 4]) = pk;
    }
  __syncthreads();

  // finalize: wave w owns d-range [w*16, w*16+16); 2 units/lane
  int q = lane & 31, hi = lane >> 5;
  float lsq = lsp[0][q] + lsp[1][q] + lsp[2][q] + lsp[3][q];  // > 0 via self-loop
  float inv = 1.f / lsq;
  int gq = q0 + q;
#pragma unroll
  for (int u = 0; u < 2; u++) {
    int c = w * 4 + hi + u * 2;          // d-chunk index, d0 = c*4
    int cs = c ^ (q & 15);
    f32x4 sum = f32x4{0.f, 0.f, 0.f, 0.f};
#pragma unroll
    for (int wv = 0; wv < 4; wv++) {
      bf16x4 rp = *reinterpret_cast<const bf16x4*>(&stage[wv][0][q * 64 + cs * 4]);
#pragma unroll
      for (int r = 0; r < 4; r++) sum[r] += (float)rp[r];
    }
    bf16x4 pk;
#pragma unroll
    for (int r = 0; r < 4; r++) pk[r] = (bf16)(sum[r] * inv);
    *reinterpret_cast<bf16x4*>(
        &attn_out[((size_t)(bb * N_SEQ + gq)) * DMODEL + hh * 64 + c * 4]) = pk;
  }
}

// ---- row LayerNorm: one block per row, bf16 h input ----
__global__ __launch_bounds__(256) void k_ln(const bf16* __restrict__ hb,
    const float* __restrict__ gamma, const float* __restrict__ beta,
    float* __restrict__ out) {
  int row = blockIdx.x, tid = threadIdx.x;
  bf16x2 v2 = *reinterpret_cast<const bf16x2*>(hb + (size_t)row * DMODEL + tid * 2);
  float vx = (float)v2[0], vy = (float)v2[1];
  float s = vx + vy, ss = vx * vx + vy * vy;
#pragma unroll
  for (int off = 1; off < 64; off <<= 1) {
    s += __shfl_xor(s, off);
    ss += __shfl_xor(ss, off);
  }
  __shared__ float as_[4], ass_[4];
  int w = tid >> 6;
  if ((tid & 63) == 0) { as_[w] = s; ass_[w] = ss; }
  __syncthreads();
  s = as_[0] + as_[1] + as_[2] + as_[3];
  ss = ass_[0] + ass_[1] + ass_[2] + ass_[3];
  float mu = s * (1.f / 512.f);
  float var = ss * (1.f / 512.f) - mu * mu;
  float rstd = rsqrtf(var + 1e-5f);
  float2 g = reinterpret_cast<const float2*>(gamma)[tid];
  float2 bt = reinterpret_cast<const float2*>(beta)[tid];
  float2 o;
  o.x = (vx - mu) * rstd * g.x + bt.x;
  o.y = (vy - mu) * rstd * g.y + bt.y;
  reinterpret_cast<float2*>(out + (size_t)row * DMODEL)[tid] = o;
}

extern "C" void kernel_launch(void* const* d_in, const int* in_sizes, int n_in,
                              void* d_out, int out_size, void* d_ws, size_t ws_size,
                              hipStream_t stream) {
  const float* x     = (const float*)d_in[0];
  const float* adj   = (const float*)d_in[1];
  const float* Wq    = (const float*)d_in[2];
  const float* bq    = (const float*)d_in[3];
  const float* Wk    = (const float*)d_in[4];
  const float* bk    = (const float*)d_in[5];
  const float* Wv    = (const float*)d_in[6];
  const float* bv    = (const float*)d_in[7];
  const float* Wo    = (const float*)d_in[8];
  const float* bo    = (const float*)d_in[9];
  const float* gamma = (const float*)d_in[10];
  const float* beta  = (const float*)d_in[11];

  char* ws = (char*)d_ws;
  bf16* xb    = (bf16*)(ws + OFF_XB);
  bf16* wqkv  = (bf16*)(ws + OFF_WQKV);
  bf16* wo    = (bf16*)(ws + OFF_WO);
  float* bqkv = (float*)(ws + OFF_BQKV);
  bf16* Qb    = (bf16*)(ws + OFF_Q);
  bf16* Kb    = (bf16*)(ws + OFF_K);
  bf16* Vb    = (bf16*)(ws + OFF_V);   // holds V^T
  u64* maskb  = (u64*)(ws + OFF_MASK);
  bf16* attn  = xb;                    // x_bf16 dead after QKV GEMM
  bf16* hb    = (bf16*)(ws + OFF_Q);   // Q/K dead after attention; h in bf16
  float* out  = (float*)d_out;

  // 1. merged prep
  k_prep<<<dim3(PREP_X_BLK + PREP_W_BLK + PREP_M_BLK), dim3(256), 0, stream>>>(
      x, adj, Wq, Wk, Wv, Wo, bq, bk, bv, xb, wqkv, wo, bqkv, maskb);

  // 2. QKV projection (M=8192, N=1536), V stored transposed, Q pre-scaled
  k_gemm<<<dim3((M_ROWS / 128) * (1536 / 128)), dim3(256), 0, stream>>>(
      xb, wqkv, 1536, 0, bqkv, nullptr, Qb, Kb, Vb, nullptr);

  // 3. masked attention (k-split, private staging, barrier-free loop)
  k_attn<<<dim3(2048), dim3(256), 0, stream>>>(Qb, Kb, Vb, maskb, attn);

  // 4. output projection + bias + residual -> h bf16 (M=8192, N=512)
  k_gemm<<<dim3((M_ROWS / 128) * (512 / 128)), dim3(256), 0, stream>>>(
      attn, wo, 512, 1, bo, x, nullptr, nullptr, nullptr, hb);

  // 5. LayerNorm
  k_ln<<<dim3(M_ROWS), dim3(256), 0, stream>>>(hb, gamma, beta, out);
}

// Round 10
// 105.666 us; speedup vs baseline: 1.2478x; 1.2478x over previous
//
#include <hip/hip_runtime.h>

typedef __bf16 bf16;
typedef bf16 bf16x8 __attribute__((ext_vector_type(8)));
typedef bf16 bf16x4 __attribute__((ext_vector_type(4)));
typedef bf16 bf16x2 __attribute__((ext_vector_type(2)));
typedef float f32x4 __attribute__((ext_vector_type(4)));
typedef unsigned long long u64;
typedef unsigned int u32;

#define B_SZ 8
#define N_SEQ 1024
#define DMODEL 512
#define N_HEADS 8
#define D_HEAD 64
#define M_ROWS 8192   // B_SZ * N_SEQ

// Q pre-scale: 1/sqrt(64) * log2(e), so softmax uses exp2 directly
#define QSCALE 0.18033688011112042f

// ---- workspace layout (bytes) ----
static constexpr size_t OFF_XB   = 0;                                   // bf16 [8192][512]; reused as attn_out later
static constexpr size_t OFF_WQKV = (size_t)M_ROWS * DMODEL * 2;         // bf16 [1536][512]
static constexpr size_t OFF_WO   = OFF_WQKV + (size_t)1536 * 512 * 2;   // bf16 [512][512]
static constexpr size_t OFF_BQKV = OFF_WO + (size_t)512 * 512 * 2;      // f32  [1536]
static constexpr size_t OFF_Q    = OFF_BQKV + 1536 * 4;                 // bf16 [64][1024][64]; later reused as h bf16
static constexpr size_t OFF_K    = OFF_Q + (size_t)64 * 1024 * 64 * 2;
static constexpr size_t OFF_V    = OFF_K + (size_t)64 * 1024 * 64 * 2;  // V^T: bf16 [64 bh][64 d][1024 n]
static constexpr size_t OFF_MASK = OFF_V + (size_t)64 * 1024 * 64 * 2;  // u64 [8][1024][16]

// k_prep block partition (256 threads each)
#define PREP_X_BLK 4096    // 8192*512 elems / 4-per-thread / 256
#define PREP_W_BLK 4102    // (1536*512 + 512*512 + 1536) / 256
#define PREP_M_BLK 32768   // 8*1024*1024 / 256

__device__ __forceinline__ f32x4 mfma16(bf16x8 a, bf16x8 b, f32x4 c) {
  return __builtin_amdgcn_mfma_f32_16x16x32_bf16(a, b, c, 0, 0, 0);
}

// XOR swizzle for [R][64] bf16 LDS tiles (row = 128B): kills the 32-way
// ds_read_b128 column conflict (guide G4 / T2). col, row in elements.
__device__ __forceinline__ int sidx(int row, int col) {
  return (row << 6) + (col ^ ((row & 7) << 3));
}

// async global->LDS, 16B per lane; LDS dest = wave-uniform base + lane*16.
__device__ __forceinline__ void gload16(const void* g, void* l) {
  __builtin_amdgcn_global_load_lds(
      (const __attribute__((address_space(1))) void*)g,
      (__attribute__((address_space(3))) void*)l, 16, 0, 0);
}

// ---- merged prep: cvt x, pack weights/biases, build mask bits ----
__global__ void k_prep(const float* __restrict__ x, const float* __restrict__ adj,
                       const float* __restrict__ Wq, const float* __restrict__ Wk,
                       const float* __restrict__ Wv, const float* __restrict__ Wo,
                       const float* __restrict__ bq, const float* __restrict__ bk,
                       const float* __restrict__ bv,
                       bf16* __restrict__ xb, bf16* __restrict__ wqkv,
                       bf16* __restrict__ wo, float* __restrict__ bqkv,
                       u64* __restrict__ maskb) {
  int b = blockIdx.x;
  if (b < PREP_X_BLK) {                 // x fp32 -> bf16, 4/thread
    int i = b * 256 + threadIdx.x;
    float4 v = reinterpret_cast<const float4*>(x)[i];
    bf16x4 o = { (bf16)v.x, (bf16)v.y, (bf16)v.z, (bf16)v.w };
    *reinterpret_cast<bf16x4*>(xb + (size_t)i * 4) = o;
  } else if (b < PREP_X_BLK + PREP_W_BLK) {  // weights/biases
    int tid = (b - PREP_X_BLK) * 256 + threadIdx.x;
    if (tid < 1536 * 512) {
      int row = tid >> 9;
      const float* Wsrc = row < 512 ? Wq : row < 1024 ? Wk : Wv;
      wqkv[tid] = (bf16)Wsrc[((row & 511) << 9) | (tid & 511)];
    } else if (tid < 1536 * 512 + 512 * 512) {
      int t = tid - 1536 * 512;
      wo[t] = (bf16)Wo[t];
    } else if (tid < 1536 * 512 + 512 * 512 + 1536) {
      int t = tid - (1536 * 512 + 512 * 512);
      bqkv[t] = t < 512 ? bq[t] : t < 1024 ? bk[t - 512] : bv[t - 1024];
    }
  } else {                              // adjacency -> bitmask with self loops
    int idx = (b - (PREP_X_BLK + PREP_W_BLK)) * 256 + threadIdx.x;
    int q = (idx >> 10) & 1023, k = idx & 1023;
    bool pred = (adj[idx] > 0.f) || (q == k);
    u64 bal = __ballot(pred);
    if ((threadIdx.x & 63) == 0) maskb[idx >> 6] = bal;
  }
}

// ---- bf16 MFMA GEMM, m97 structure + XCD-aware block swizzle (T1) ----
// mode 0: scatter Q (pre-scaled QSCALE) / K bf16 into [b,h,n,d], V into V^T [b,h,d,n]
// mode 1: h = acc + bias + x, stored bf16
__global__ __launch_bounds__(256) void k_gemm(const bf16* __restrict__ A,
    const bf16* __restrict__ W, int ncols, int mode,
    const float* __restrict__ bias, const float* __restrict__ xres,
    bf16* __restrict__ oq, bf16* __restrict__ okk, bf16* __restrict__ ov,
    bf16* __restrict__ oh) {
  __shared__ bf16 Al[128 * 64];
  __shared__ bf16 Bl[128 * 64];
  int nbx = ncols >> 7;
  // XCD swizzle (gridDim.x % 8 == 0 for both calls: 768, 256). Consecutive
  // wid within an XCD sweep bx (N) fastest -> A-strip stays in that XCD's L2.
  int cpx = gridDim.x >> 3;
  int wid = (blockIdx.x & 7) * cpx + (blockIdx.x >> 3);
  int bx = wid % nbx, by = wid / nbx;
  int m0 = by << 7, n0 = bx << 7;
  int tid = threadIdx.x, lane = tid & 63, w = tid >> 6;
  int wr = (w >> 1) << 6, wc = (w & 1) << 6;
  int lrow = lane & 15, lg = lane >> 4, lko = lg * 8;
  int rl = lane >> 3;                   // row-in-group 0..7
  int csw = ((lane & 7) ^ rl) << 3;     // pre-swizzled col (elements)

  const bf16* Asrc = A + (size_t)(m0 + w * 32 + rl) * DMODEL + csw;
  const bf16* Wsrc = W + (size_t)(n0 + w * 32 + rl) * DMODEL + csw;
  bf16* Adst = &Al[(w * 4) * 512];
  bf16* Bdst = &Bl[(w * 4) * 512];

  f32x4 acc[4][4];
#pragma unroll
  for (int i = 0; i < 4; i++)
#pragma unroll
    for (int j = 0; j < 4; j++) acc[i][j] = f32x4{0.f, 0.f, 0.f, 0.f};

  for (int k0 = 0; k0 < DMODEL; k0 += 64) {
    __syncthreads();
#pragma unroll
    for (int i = 0; i < 4; i++) {
      gload16(Asrc + k0 + (size_t)i * 8 * DMODEL, Adst + i * 512);
      gload16(Wsrc + k0 + (size_t)i * 8 * DMODEL, Bdst + i * 512);
    }
    __syncthreads();

    bf16x8 afr[4][2], bfr[4][2];
#pragma unroll
    for (int i = 0; i < 4; i++) {
      afr[i][0] = *reinterpret_cast<const bf16x8*>(&Al[sidx(wr + i * 16 + lrow, lko)]);
      afr[i][1] = *reinterpret_cast<const bf16x8*>(&Al[sidx(wr + i * 16 + lrow, 32 + lko)]);
      bfr[i][0] = *reinterpret_cast<const bf16x8*>(&Bl[sidx(wc + i * 16 + lrow, lko)]);
      bfr[i][1] = *reinterpret_cast<const bf16x8*>(&Bl[sidx(wc + i * 16 + lrow, 32 + lko)]);
    }
#pragma unroll
    for (int i = 0; i < 4; i++)
#pragma unroll
      for (int j = 0; j < 4; j++) {
        acc[i][j] = mfma16(afr[i][0], bfr[j][0], acc[i][j]);
        acc[i][j] = mfma16(afr[i][1], bfr[j][1], acc[i][j]);
      }
  }

  int rbase = lg * 4;
  if (mode == 0) {
#pragma unroll
    for (int i = 0; i < 4; i++) {
      int row0 = m0 + wr + i * 16 + rbase;
#pragma unroll
      for (int j = 0; j < 4; j++) {
        int col = n0 + wc + j * 16 + lrow;
        int which = col >> 9, c2 = col & 511, hh = c2 >> 6, dd = c2 & 63;
        float bi = bias[col];
        if (which == 2) {
          int bb = row0 >> 10, nn = row0 & 1023;
          bf16x4 pack;
#pragma unroll
          for (int r = 0; r < 4; r++) pack[r] = (bf16)(acc[i][j][r] + bi);
          *reinterpret_cast<bf16x4*>(
              &ov[(((size_t)bb * N_HEADS + hh) * D_HEAD + dd) * N_SEQ + nn]) = pack;
        } else {
          bf16* dst = which == 0 ? oq : okk;
          float scl = which == 0 ? QSCALE : 1.0f;
#pragma unroll
          for (int r = 0; r < 4; r++) {
            int gm = row0 + r;
            int bb = gm >> 10, nn = gm & 1023;
            dst[(((size_t)bb * N_HEADS + hh) * N_SEQ + nn) * D_HEAD + dd] =
                (bf16)((acc[i][j][r] + bi) * scl);
          }
        }
      }
    }
  } else {
#pragma unroll
    for (int i = 0; i < 4; i++) {
      int row0 = m0 + wr + i * 16 + rbase;
#pragma unroll
      for (int j = 0; j < 4; j++) {
        int col = n0 + wc + j * 16 + lrow;
        float bi = bias[col];
#pragma unroll
        for (int r = 0; r < 4; r++) {
          int gm = row0 + r;
          float y = acc[i][j][r] + bi + xres[(size_t)gm * DMODEL + col];
          oh[(size_t)gm * DMODEL + col] = (bf16)y;
        }
      }
    }
  }
}

// ---- masked attention: LDS-staged K/V + in-register P (round-8 structure) ----
// + T5 setprio around MFMA clusters, masks as 2x u32 (no 64-bit shifts).
// Block = 64 q-rows of one (b,h); 4 waves x 16 q-rows. K/V^T double-buffered
// via global_load_lds, ONE barrier per tile. Swapped QK^T (mfma(K,Q)) gives
// S^T at lane q=lane&15, k=lg*4+r; P stays in registers and feeds PV as the
// B-operand with paired k-subtiles; V^T A-fragments read as 2x ds_read_b64.
// grid 1024 XCD-swizzled: each XCD owns 8 (b,h) pairs (K/V 2MB < 4MB L2).
__global__ __launch_bounds__(256, 4) void k_attn(const bf16* __restrict__ Qb,
    const bf16* __restrict__ Kb, const bf16* __restrict__ Vtg,
    const u64* __restrict__ maskb, bf16* __restrict__ attn_out) {
  __shared__ bf16 Kl[2][64 * 64];
  __shared__ bf16 Vt[2][64 * 64];

  int bid = blockIdx.x;
  int work = ((bid & 7) << 7) | (bid >> 3);  // XCD swizzle (1024 = 8*128, bijective)
  int bh = work >> 4, qb = work & 15;
  int bb = bh >> 3, hh = bh & 7;
  int tid = threadIdx.x, lane = tid & 63, w = tid >> 6;
  int lrow = lane & 15, lg = lane >> 4;
  int rl = lane >> 3;
  int csw = ((lane & 7) ^ rl) << 3;
  int q0w = qb * 64 + w * 16;

  const bf16* Qh = Qb + (size_t)bh * N_SEQ * D_HEAD;
  const bf16* Kh = Kb + (size_t)bh * N_SEQ * D_HEAD;
  const bf16* Vh = Vtg + (size_t)bh * D_HEAD * N_SEQ;  // [d][n]
  const u32* m32 = (const u32*)(maskb + (size_t)bb * N_SEQ * 16);

  // per-lane staging sources (wave w stages rows w*16 .. w*16+15 of each tile)
  const bf16* Ksrc = Kh + (size_t)(w * 16 + rl) * D_HEAD + csw;
  const bf16* Vsrc = Vh + (size_t)(w * 16 + rl) * N_SEQ + csw;

  // Q fragments (B-operand of swapped QK^T): lane holds Q[q=q0w+lrow][d-slice]
  bf16x8 qf0 = *reinterpret_cast<const bf16x8*>(&Qh[(q0w + lrow) * 64 + lg * 8]);
  bf16x8 qf1 = *reinterpret_cast<const bf16x8*>(&Qh[(q0w + lrow) * 64 + 32 + lg * 8]);

  f32x4 o[4];   // o[dblk][r] = O[q=lrow][d=dblk*16+lg*4+r]
#pragma unroll
  for (int d = 0; d < 4; d++) o[d] = f32x4{0.f, 0.f, 0.f, 0.f};
  float ls = 0.f;  // per-lane partial row-sum (q=lrow, k-slice)

#define STAGE(buf, kt0)                                                     \
  {                                                                         \
    _Pragma("unroll") for (int i = 0; i < 2; i++) {                         \
      gload16(Ksrc + (size_t)(kt0) * 64 + i * 512, &Kl[buf][(w * 2 + i) * 512]); \
      gload16(Vsrc + (size_t)i * 8192 + (kt0), &Vt[buf][(w * 2 + i) * 512]);     \
    }                                                                       \
  }

  STAGE(0, 0);
  __syncthreads();
  int cur = 0;

  for (int kt = 0; kt < 16; kt++) {
    int kt0 = kt << 6;
    int midx = ((q0w + lrow) * 16 + kt) * 2;
    u32 mlo = m32[midx], mhi = m32[midx + 1];   // k bits [0,32) / [32,64)

    if (kt < 15) STAGE(cur ^ 1, kt0 + 64);  // prefetch next tile

    // swapped QK^T: sc[t][r] = S[q=lrow][k = kt*64 + t*16 + lg*4 + r]
    f32x4 sc[4];
#pragma unroll
    for (int t = 0; t < 4; t++) {
      bf16x8 kf0 = *reinterpret_cast<const bf16x8*>(&Kl[cur][sidx(t * 16 + lrow, lg * 8)]);
      bf16x8 kf1 = *reinterpret_cast<const bf16x8*>(&Kl[cur][sidx(t * 16 + lrow, 32 + lg * 8)]);
      sc[t] = f32x4{0.f, 0.f, 0.f, 0.f};
      __builtin_amdgcn_s_setprio(1);
      sc[t] = mfma16(kf0, qf0, sc[t]);
      sc[t] = mfma16(kf1, qf1, sc[t]);
      __builtin_amdgcn_s_setprio(0);
    }

    // p = mask ? exp2(s) : 0, packed as PV B-fragments: pa[m][j] holds
    // P[q][k = m*32 + (j>>2)*16 + lg*4 + (j&3)]; m selects u32 mask word.
    bf16x8 pa[2];
#pragma unroll
    for (int m = 0; m < 2; m++) {
      u32 mw = m == 0 ? mlo : mhi;
#pragma unroll
      for (int j = 0; j < 8; j++) {
        int sh = ((j >> 2) << 4) + lg * 4 + (j & 3);
        int t = 2 * m + (j >> 2), r = j & 3;
        bool bit = (mw >> sh) & 1u;
        float pv = bit ? exp2f(sc[t][r]) : 0.f;
        ls += pv;
        pa[m][j] = (bf16)pv;
      }
    }

    // PV: A-frag vf[j] = V^T[dblk*16+lrow][same k map] via 2x ds_read_b64
#pragma unroll
    for (int d = 0; d < 4; d++) {
#pragma unroll
      for (int m = 0; m < 2; m++) {
        bf16x4 va = *reinterpret_cast<const bf16x4*>(
            &Vt[cur][sidx(d * 16 + lrow, m * 32 + lg * 4)]);
        bf16x4 vb = *reinterpret_cast<const bf16x4*>(
            &Vt[cur][sidx(d * 16 + lrow, m * 32 + 16 + lg * 4)]);
        bf16x8 vf = {va[0], va[1], va[2], va[3], vb[0], vb[1], vb[2], vb[3]};
        __builtin_amdgcn_s_setprio(1);
        o[d] = mfma16(vf, pa[m], o[d]);
        __builtin_amdgcn_s_setprio(0);
      }
    }

    __syncthreads();  // all waves done with buf[cur]; next tile's gloads landed
    cur ^= 1;
  }

  // row-sum: reduce over the 4 lane-groups (k slices); q=lrow
  ls += __shfl_xor(ls, 16);
  ls += __shfl_xor(ls, 32);
  float inv = 1.f / ls;  // l > 0 via self-loop

  int gq = q0w + lrow;
#pragma unroll
  for (int d = 0; d < 4; d++) {
    bf16x4 pk;
#pragma unroll
    for (int r = 0; r < 4; r++) pk[r] = (bf16)(o[d][r] * inv);
    *reinterpret_cast<bf16x4*>(
        &attn_out[((size_t)(bb * N_SEQ + gq)) * DMODEL + hh * 64 + d * 16 + lg * 4]) = pk;
  }
#undef STAGE
}

// ---- row LayerNorm: one block per row, bf16 h input ----
__global__ __launch_bounds__(256) void k_ln(const bf16* __restrict__ hb,
    const float* __restrict__ gamma, const float* __restrict__ beta,
    float* __restrict__ out) {
  int row = blockIdx.x, tid = threadIdx.x;
  bf16x2 v2 = *reinterpret_cast<const bf16x2*>(hb + (size_t)row * DMODEL + tid * 2);
  float vx = (float)v2[0], vy = (float)v2[1];
  float s = vx + vy, ss = vx * vx + vy * vy;
#pragma unroll
  for (int off = 1; off < 64; off <<= 1) {
    s += __shfl_xor(s, off);
    ss += __shfl_xor(ss, off);
  }
  __shared__ float as_[4], ass_[4];
  int w = tid >> 6;
  if ((tid & 63) == 0) { as_[w] = s; ass_[w] = ss; }
  __syncthreads();
  s = as_[0] + as_[1] + as_[2] + as_[3];
  ss = ass_[0] + ass_[1] + ass_[2] + ass_[3];
  float mu = s * (1.f / 512.f);
  float var = ss * (1.f / 512.f) - mu * mu;
  float rstd = rsqrtf(var + 1e-5f);
  float2 g = reinterpret_cast<const float2*>(gamma)[tid];
  float2 bt = reinterpret_cast<const float2*>(beta)[tid];
  float2 o;
  o.x = (vx - mu) * rstd * g.x + bt.x;
  o.y = (vy - mu) * rstd * g.y + bt.y;
  reinterpret_cast<float2*>(out + (size_t)row * DMODEL)[tid] = o;
}

extern "C" void kernel_launch(void* const* d_in, const int* in_sizes, int n_in,
                              void* d_out, int out_size, void* d_ws, size_t ws_size,
                              hipStream_t stream) {
  const float* x     = (const float*)d_in[0];
  const float* adj   = (const float*)d_in[1];
  const float* Wq    = (const float*)d_in[2];
  const float* bq    = (const float*)d_in[3];
  const float* Wk    = (const float*)d_in[4];
  const float* bk    = (const float*)d_in[5];
  const float* Wv    = (const float*)d_in[6];
  const float* bv    = (const float*)d_in[7];
  const float* Wo    = (const float*)d_in[8];
  const float* bo    = (const float*)d_in[9];
  const float* gamma = (const float*)d_in[10];
  const float* beta  = (const float*)d_in[11];

  char* ws = (char*)d_ws;
  bf16* xb    = (bf16*)(ws + OFF_XB);
  bf16* wqkv  = (bf16*)(ws + OFF_WQKV);
  bf16* wo    = (bf16*)(ws + OFF_WO);
  float* bqkv = (float*)(ws + OFF_BQKV);
  bf16* Qb    = (bf16*)(ws + OFF_Q);
  bf16* Kb    = (bf16*)(ws + OFF_K);
  bf16* Vb    = (bf16*)(ws + OFF_V);   // holds V^T
  u64* maskb  = (u64*)(ws + OFF_MASK);
  bf16* attn  = xb;                    // x_bf16 dead after QKV GEMM
  bf16* hb    = (bf16*)(ws + OFF_Q);   // Q/K dead after attention; h in bf16
  float* out  = (float*)d_out;

  // 1. merged prep
  k_prep<<<dim3(PREP_X_BLK + PREP_W_BLK + PREP_M_BLK), dim3(256), 0, stream>>>(
      x, adj, Wq, Wk, Wv, Wo, bq, bk, bv, xb, wqkv, wo, bqkv, maskb);

  // 2. QKV projection (M=8192, N=1536), V stored transposed, Q pre-scaled
  k_gemm<<<dim3((M_ROWS / 128) * (1536 / 128)), dim3(256), 0, stream>>>(
      xb, wqkv, 1536, 0, bqkv, nullptr, Qb, Kb, Vb, nullptr);

  // 3. masked attention (round-8 structure + setprio + u32 masks)
  k_attn<<<dim3(1024), dim3(256), 0, stream>>>(Qb, Kb, Vb, maskb, attn);

  // 4. output projection + bias + residual -> h bf16 (M=8192, N=512)
  k_gemm<<<dim3((M_ROWS / 128) * (512 / 128)), dim3(256), 0, stream>>>(
      attn, wo, 512, 1, bo, x, nullptr, nullptr, nullptr, hb);

  // 5. LayerNorm
  k_ln<<<dim3(M_ROWS), dim3(256), 0, stream>>>(hb, gamma, beta, out);
}